// Round 17
// baseline (153.573 us; speedup 1.0000x reference)
//
#include <hip/hip_runtime.h>
#include <hip/hip_bf16.h>
#include <stdint.h>

// ---------- types & helpers ----------
typedef __attribute__((ext_vector_type(8))) short bf16x8;    // 8 bf16 (4 VGPRs)
typedef __attribute__((ext_vector_type(4))) float f32x4;     // 16x16 MFMA acc
typedef __attribute__((ext_vector_type(16))) float f32x16;   // 32x32 MFMA acc
typedef unsigned int u32;

#define MFMA16(a,b,c) __builtin_amdgcn_mfma_f32_16x16x32_bf16((a),(b),(c),0,0,0)
#define MFMA32(a,b,c) __builtin_amdgcn_mfma_f32_32x32x16_bf16((a),(b),(c),0,0,0)

__device__ __forceinline__ unsigned short f2bf(float f) {
    unsigned u = __float_as_uint(f);
    u = (u + 0x7FFFu + ((u >> 16) & 1u)) >> 16;   // RNE
    return (unsigned short)u;
}
__device__ __forceinline__ float bf2f(unsigned short h) {
    return __uint_as_float(((unsigned)h) << 16);
}
// 2x f32 -> packed bf16 pair (RNE), single VALU op
__device__ __forceinline__ u32 cvt_pk_bf16(float lo, float hi) {
    u32 r;
    asm("v_cvt_pk_bf16_f32 %0, %1, %2" : "=v"(r) : "v"(lo), "v"(hi));
    return r;
}
// async global->LDS, 16B per lane; lds base must be wave-uniform
__device__ __forceinline__ void gload16(const unsigned short* gp, unsigned short* lp) {
    __builtin_amdgcn_global_load_lds(
        (const __attribute__((address_space(1))) u32*)gp,
        (__attribute__((address_space(3))) u32*)lp, 16, 0, 0);
}
// bijective XCD chunking: nwg = q8*8
__device__ __forceinline__ int xcd_swz(int bid, int q8) {
    return (bid & 7) * q8 + (bid >> 3);
}

// Problem constants: 32 flattened batch, T=512, D=512, H=8, DK=DV=64

// ---------- kernel 0: fp32 -> bf16 prepass, one chunk per thread ----------
__global__ __launch_bounds__(256) void prep_kernel(
    const float* __restrict__ q, const float* __restrict__ k, const float* __restrict__ v,
    const float* __restrict__ wq, const float* __restrict__ wk, const float* __restrict__ wv,
    const float* __restrict__ wfc,
    unsigned short* __restrict__ Xq, unsigned short* __restrict__ Xk, unsigned short* __restrict__ Xv,
    unsigned short* __restrict__ Wcat)
{
    const long c = (long)blockIdx.x * 256 + threadIdx.x;
    const float* src;
    unsigned short* dst;
    long off;
    if (c < 3145728) {                 // X tensors: 1,048,576 chunks each
        const int t = (int)(c >> 20);
        off = (c & 1048575) * 8;
        src = (t == 0) ? q : (t == 1) ? k : v;
        dst = (t == 0) ? Xq : (t == 1) ? Xk : Xv;
    } else {                           // weights: 32768 chunks each
        const long c2 = c - 3145728;
        const int w = (int)(c2 >> 15);
        off = (c2 & 32767) * 8;
        src = (w == 0) ? wq : (w == 1) ? wk : (w == 2) ? wv : wfc;
        dst = Wcat + (long)w * 262144;
    }
    const float4 a = *(const float4*)(src + off);
    const float4 b = *(const float4*)(src + off + 4);
    uint4 pk;
    pk.x = (u32)f2bf(a.x) | ((u32)f2bf(a.y) << 16);
    pk.y = (u32)f2bf(a.z) | ((u32)f2bf(a.w) << 16);
    pk.z = (u32)f2bf(b.x) | ((u32)f2bf(b.y) << 16);
    pk.w = (u32)f2bf(b.z) | ((u32)f2bf(b.w) << 16);
    *(uint4*)(dst + off) = pk;
}

// ---------- GEMM body: A direct-from-global into MFMA regs, B LDS dbuf ----------
// r16 diagnosis: 64KB LDS capped proj at 2 blocks/CU; barrier drain exposed
// staged-load latency. A-fragments are contiguous 16B per lane -> load them
// straight from global (L2/L3-hot) into operand regs at step t for t+1.
// LDS holds only the B weight panel (2 x 16 KB dbuf) -> ~3 blocks/CU.
__device__ __forceinline__ void gemm_body(
    const unsigned short* __restrict__ A, const unsigned short* __restrict__ Bm,
    unsigned short* __restrict__ out, int mode, float scale,
    unsigned short* Bs0, unsigned short* Bs1,
    int m0, int n0)
{
    const int tid = threadIdx.x, wid = tid >> 6, lane = tid & 63;
    const int wm = wid >> 1, wn = wid & 1;          // 2x2 waves, 64x64 each
    const int g = lane >> 4, cc = lane & 15;

    f32x4 acc[4][4];
    #pragma unroll
    for (int a = 0; a < 4; a++)
        #pragma unroll
        for (int b = 0; b < 4; b++)
            acc[a][b] = (f32x4){0.f, 0.f, 0.f, 0.f};

    // B tile 128x64 bf16 = 1024 16B-slots; 4 per thread, XOR-swizzled source
    auto STAGEB = [&](unsigned short* Bs, int k0) {
        #pragma unroll
        for (int j = 0; j < 4; j++) {
            const int sb = j * 256 + wid * 64;       // wave-uniform slot base
            const int s = sb + lane;
            const int r = s >> 3;
            const int cd = (s & 7) ^ (r & 7);
            gload16(Bm + (size_t)(n0 + r) * 512 + k0 + cd * 8, Bs + (size_t)sb * 8);
        }
    };
    // A fragments for one K-step, direct from global (row-contiguous 16B)
    const unsigned short* Arow = A + (size_t)(m0 + wm * 64 + cc) * 512 + g * 8;
    auto LOADA = [&](bf16x8 (&af)[4][2], int k0) {
        #pragma unroll
        for (int mf = 0; mf < 4; mf++)
            #pragma unroll
            for (int kc = 0; kc < 2; kc++)
                af[mf][kc] = *(const bf16x8*)(Arow + (size_t)(mf * 16) * 512 + k0 + kc * 32);
    };

    bf16x8 aA[4][2], aB[4][2];
    LOADA(aA, 0);
    STAGEB(Bs0, 0);
    __syncthreads();

    #pragma unroll
    for (int t = 0; t < 8; t++) {
        auto& acur = (t & 1) ? aB : aA;
        auto& anext = (t & 1) ? aA : aB;
        unsigned short* Bc = (t & 1) ? Bs1 : Bs0;
        unsigned short* Bn = (t & 1) ? Bs0 : Bs1;
        if (t < 7) {
            LOADA(anext, (t + 1) * 64);              // in flight across this step
            STAGEB(Bn, (t + 1) * 64);
        }

        #pragma unroll
        for (int kc = 0; kc < 2; kc++) {
            bf16x8 bfr[4];
            #pragma unroll
            for (int nf = 0; nf < 4; nf++) {
                const int r = wn * 64 + nf * 16 + cc;
                bfr[nf] = *(const bf16x8*)(Bc + r * 64 + (((kc * 4 + g) ^ (r & 7)) * 8));
            }
            __builtin_amdgcn_s_setprio(1);
            #pragma unroll
            for (int mf = 0; mf < 4; mf++)
                #pragma unroll
                for (int nf = 0; nf < 4; nf++)
                    acc[mf][nf] = MFMA16(acur[mf][kc], bfr[nf], acc[mf][nf]);
            __builtin_amdgcn_s_setprio(0);
        }
        __syncthreads();   // B(t+1) landed; Bc free for restage
    }

    #pragma unroll
    for (int mf = 0; mf < 4; mf++) {
        const int rg = m0 + wm * 64 + mf * 16 + g * 4;
        const int t0 = rg & 511, bI = rg >> 9;
        #pragma unroll
        for (int nf = 0; nf < 4; nf++) {
            const int col = n0 + wn * 64 + nf * 16 + cc;
            if (mode == 0) {
                const int h = col >> 6, dd = col & 63;
                const size_t base = ((size_t)((bI * 8 + h) * 512 + t0)) * 64 + dd;
                #pragma unroll
                for (int i = 0; i < 4; i++)
                    out[base + (size_t)i * 64] = f2bf(acc[mf][nf][i] * scale);
            } else if (mode == 1) {
                const int h = col >> 6, dd = col & 63;
                const size_t base = ((size_t)((bI * 8 + h) * 64 + dd)) * 512 + t0;
                uint2 pk;
                pk.x = (u32)f2bf(acc[mf][nf][0]) | ((u32)f2bf(acc[mf][nf][1]) << 16);
                pk.y = (u32)f2bf(acc[mf][nf][2]) | ((u32)f2bf(acc[mf][nf][3]) << 16);
                *(uint2*)(out + base) = pk;
            } else {
                #pragma unroll
                for (int i = 0; i < 4; i++)
                    out[(size_t)(rg + i) * 512 + col] = f2bf(acc[mf][nf][i]);
            }
        }
    }
}

// ---------- kernel 1a: merged Q/K/V projection GEMMs ----------
__global__ __launch_bounds__(256) void proj_kernel(
    const unsigned short* __restrict__ Xq, const unsigned short* __restrict__ Xk,
    const unsigned short* __restrict__ Xv, const unsigned short* __restrict__ Wcat,
    unsigned short* __restrict__ Qb, unsigned short* __restrict__ Kb,
    unsigned short* __restrict__ Vt)
{
    __shared__ __align__(16) unsigned short Bs[2][128 * 64];   // 2 x 16 KB
    const int work = xcd_swz(blockIdx.x, 192);       // nwg = 1536
    const int x = work & 3, y = (work >> 2) & 127, z = work >> 9;
    const unsigned short* A = (z == 0) ? Xq : (z == 1) ? Xk : Xv;
    const unsigned short* B = Wcat + (size_t)z * 262144;
    unsigned short* out = (z == 0) ? Qb : (z == 1) ? Kb : Vt;
    const int mode = (z == 2) ? 1 : 0;
    const float scale = (z == 0) ? 0.125f : 1.0f;
    gemm_body(A, B, out, mode, scale, Bs[0], Bs[1], y * 128, x * 128);
}

// ---------- kernel 1b: fc GEMM ----------
__global__ __launch_bounds__(256) void fc_kernel(
    const unsigned short* __restrict__ Os, const unsigned short* __restrict__ Wfc,
    unsigned short* __restrict__ Y)
{
    __shared__ __align__(16) unsigned short Bs[2][128 * 64];   // 2 x 16 KB
    const int work = xcd_swz(blockIdx.x, 64);        // nwg = 512
    const int x = work & 3, y = work >> 2;
    gemm_body(Os, Wfc, Y, 2, 1.0f, Bs[0], Bs[1], y * 128, x * 128);
}

// ---------- kernel 2: flash attention, 32x32 swapped-QK^T, P-in-registers ----------
// (r16-verified: single-buffered staging, permlane32_swap half-exchange)
__global__ __launch_bounds__(256) void attn_kernel(
    const unsigned short* __restrict__ Qb, const unsigned short* __restrict__ Kb,
    const unsigned short* __restrict__ Vt, unsigned short* __restrict__ Os)
{
    __shared__ __align__(16) unsigned short Ks[64 * 64];   // 8 KB
    __shared__ __align__(16) unsigned short Vs[64 * 64];   // 8 KB

    const int work = xcd_swz(blockIdx.x, 128);       // nwg = 1024
    const int qt = work & 3, bh = work >> 2;
    const int tid = threadIdx.x;
    const int wid = tid >> 6, lane = tid & 63;
    const int l31 = lane & 31, hi = lane >> 5;

    const unsigned short* Qp = Qb + (size_t)bh * 512 * 64;
    const unsigned short* Kp = Kb + (size_t)bh * 512 * 64;
    const unsigned short* Vp = Vt + (size_t)bh * 64 * 512;

    const int q0 = qt * 128 + wid * 32;              // wave covers q0..q0+31

    bf16x8 qf[4];
    #pragma unroll
    for (int c = 0; c < 4; c++)
        qf[c] = *(const bf16x8*)(Qp + (size_t)(q0 + l31) * 64 + c * 16 + hi * 8);

    f32x16 o0, o1;                                   // O[q regs][dv=l31 / 32+l31]
    #pragma unroll
    for (int r = 0; r < 16; r++) { o0[r] = 0.f; o1[r] = 0.f; }
    float lrun = 0.f;

    const int sb = wid * 64;
    const int s1 = sb + lane, r1 = s1 >> 3, cd1 = (s1 & 7) ^ (r1 & 7);
    const int s2 = sb + 256 + lane, r2 = s2 >> 3, cd2 = (s2 & 7) ^ (r2 & 7);

    const int swz0 = l31 & 7;

    for (int kt = 0; kt < 8; kt++) {
        gload16(Kp + (size_t)(kt * 64 + r1) * 64 + cd1 * 8, Ks + (size_t)sb * 8);
        gload16(Kp + (size_t)(kt * 64 + r2) * 64 + cd2 * 8, Ks + (size_t)(sb + 256) * 8);
        gload16(Vp + (size_t)r1 * 512 + kt * 64 + cd1 * 8, Vs + (size_t)sb * 8);
        gload16(Vp + (size_t)r2 * 512 + kt * 64 + cd2 * 8, Vs + (size_t)(sb + 256) * 8);
        __syncthreads();

        f32x16 sT0, sT1;
        #pragma unroll
        for (int r = 0; r < 16; r++) { sT0[r] = 0.f; sT1[r] = 0.f; }
        __builtin_amdgcn_s_setprio(1);
        #pragma unroll
        for (int c = 0; c < 4; c++) {
            const int cs = c * 2 + hi;
            bf16x8 kf0 = *(const bf16x8*)(Ks + l31 * 64 + ((cs ^ swz0) * 8));
            bf16x8 kf1 = *(const bf16x8*)(Ks + (32 + l31) * 64 + ((cs ^ swz0) * 8));
            sT0 = MFMA32(kf0, qf[c], sT0);
            sT1 = MFMA32(kf1, qf[c], sT1);
        }
        __builtin_amdgcn_s_setprio(0);

        // shift-free softmax numerator; pack P to bf16 pairs (lane-local)
        u32 wA[8], wB[8];
        #pragma unroll
        for (int j = 0; j < 8; j++) {
            float a0 = __expf(sT0[2 * j]), a1 = __expf(sT0[2 * j + 1]);
            float b0 = __expf(sT1[2 * j]), b1 = __expf(sT1[2 * j + 1]);
            lrun += (a0 + a1) + (b0 + b1);
            wA[j] = cvt_pk_bf16(a0, a1);
            wB[j] = cvt_pk_bf16(b0, b1);
        }
        // half-exchange via permlane32_swap: after swap(w[jb+i], w[jb+i+2]),
        // w[jb+i] holds PV A-fragment word i for this lane.
        #pragma unroll
        for (int jb = 0; jb < 8; jb += 4) {
            asm("v_permlane32_swap_b32 %0, %1" : "+v"(wA[jb + 0]), "+v"(wA[jb + 2]));
            asm("v_permlane32_swap_b32 %0, %1" : "+v"(wA[jb + 1]), "+v"(wA[jb + 3]));
            asm("v_permlane32_swap_b32 %0, %1" : "+v"(wB[jb + 0]), "+v"(wB[jb + 2]));
            asm("v_permlane32_swap_b32 %0, %1" : "+v"(wB[jb + 1]), "+v"(wB[jb + 3]));
        }

        __builtin_amdgcn_s_setprio(1);
        #pragma unroll
        for (int ck = 0; ck < 4; ck++) {
            const u32* w = (ck < 2) ? wA : wB;
            const int jb = (ck & 1) * 4;
            union { u32 u[4]; bf16x8 v; } pa;
            pa.u[0] = w[jb + 0];
            pa.u[1] = w[jb + 1];
            pa.u[2] = w[jb + 2];
            pa.u[3] = w[jb + 3];
            const int cs = ck * 2 + hi;
            bf16x8 vb0 = *(const bf16x8*)(Vs + l31 * 64 + ((cs ^ swz0) * 8));
            bf16x8 vb1 = *(const bf16x8*)(Vs + (32 + l31) * 64 + ((cs ^ swz0) * 8));
            o0 = MFMA32(pa.v, vb0, o0);
            o1 = MFMA32(pa.v, vb1, o1);
        }
        __builtin_amdgcn_s_setprio(0);
        __syncthreads();
    }

    const float lsum = lrun + __shfl_xor(lrun, 32);
    const float inv = 1.0f / lsum;
    float iv[16];
    #pragma unroll
    for (int qd = 0; qd < 4; qd++)
        #pragma unroll
        for (int i = 0; i < 4; i++)
            iv[qd * 4 + i] = __shfl(inv, qd * 8 + 4 * hi + i);

    const int b = bh >> 3, h = bh & 7;
    #pragma unroll
    for (int dvt = 0; dvt < 2; dvt++) {
        const f32x16& o = dvt ? o1 : o0;
        const int dv = dvt * 32 + l31;
        const size_t rowbase = ((size_t)b * 512 + h * 64 + dv) * 512;
        #pragma unroll
        for (int qd = 0; qd < 4; qd++) {
            uint2 pk;
            pk.x = cvt_pk_bf16(o[qd * 4 + 0] * iv[qd * 4 + 0], o[qd * 4 + 1] * iv[qd * 4 + 1]);
            pk.y = cvt_pk_bf16(o[qd * 4 + 2] * iv[qd * 4 + 2], o[qd * 4 + 3] * iv[qd * 4 + 3]);
            *(uint2*)(Os + rowbase + q0 + qd * 8 + 4 * hi) = pk;
        }
    }
}

// ---------- kernel 3: residual + LayerNorm (bf16 residual from Xq) ----------
__global__ __launch_bounds__(256) void ln_kernel(
    const unsigned short* __restrict__ y, const unsigned short* __restrict__ residb,
    const float* __restrict__ gamma, const float* __restrict__ beta,
    float* __restrict__ out)
{
    const int wid = threadIdx.x >> 6, lane = threadIdx.x & 63;
    const int row = blockIdx.x * 4 + wid;

    const bf16x8 yv = *(const bf16x8*)(y + (size_t)row * 512 + lane * 8);
    const bf16x8 rv = *(const bf16x8*)(residb + (size_t)row * 512 + lane * 8);
    float x[8];
    #pragma unroll
    for (int j = 0; j < 8; j++)
        x[j] = bf2f((unsigned short)yv[j]) + bf2f((unsigned short)rv[j]);

    float s = 0.f, sq = 0.f;
    #pragma unroll
    for (int j = 0; j < 8; j++) { s += x[j]; sq += x[j] * x[j]; }
    #pragma unroll
    for (int d = 1; d < 64; d <<= 1) {
        s += __shfl_xor(s, d);
        sq += __shfl_xor(sq, d);
    }
    const float mu = s * (1.0f / 512.0f);
    const float var = sq * (1.0f / 512.0f) - mu * mu;
    const float rs = rsqrtf(var + 1e-6f);

    #pragma unroll
    for (int j = 0; j < 2; j++) {
        const int colb = lane * 8 + j * 4;
        const float4 gg = *(const float4*)(gamma + colb);
        const float4 bb = *(const float4*)(beta + colb);
        float4 ov;
        ov.x = (x[j * 4 + 0] - mu) * rs * gg.x + bb.x;
        ov.y = (x[j * 4 + 1] - mu) * rs * gg.y + bb.y;
        ov.z = (x[j * 4 + 2] - mu) * rs * gg.z + bb.z;
        ov.w = (x[j * 4 + 3] - mu) * rs * gg.w + bb.w;
        *(float4*)(out + (size_t)row * 512 + colb) = ov;
    }
}

// ---------- launch ----------
// ws (98 MB): Xq | Xk | Xv | Qb | Kb | Vt (16 MB each) | Wcat (2 MB)
// aliases: Os = Xv (dead after proj), Y = Xk (dead after proj); Xq stays
// alive as the bf16 residual for ln.
extern "C" void kernel_launch(void* const* d_in, const int* in_sizes, int n_in,
                              void* d_out, int out_size, void* d_ws, size_t ws_size,
                              hipStream_t stream) {
    const float* q     = (const float*)d_in[0];
    const float* k     = (const float*)d_in[1];
    const float* v     = (const float*)d_in[2];
    const float* wq    = (const float*)d_in[3];
    const float* wk    = (const float*)d_in[4];
    const float* wv    = (const float*)d_in[5];
    const float* wfc   = (const float*)d_in[6];
    const float* gamma = (const float*)d_in[7];
    const float* beta  = (const float*)d_in[8];
    float* out = (float*)d_out;

    char* ws = (char*)d_ws;
    const size_t SEG = 16777216;
    unsigned short* Xq   = (unsigned short*)(ws);
    unsigned short* Xk   = (unsigned short*)(ws + SEG);
    unsigned short* Xv   = (unsigned short*)(ws + 2 * SEG);
    unsigned short* Qb   = (unsigned short*)(ws + 3 * SEG);
    unsigned short* Kb   = (unsigned short*)(ws + 4 * SEG);
    unsigned short* Vt   = (unsigned short*)(ws + 5 * SEG);
    unsigned short* Wcat = (unsigned short*)(ws + 6 * SEG);
    unsigned short* Os = Xv;   // attn output reuses Xv
    unsigned short* Y  = Xk;   // fc output reuses Xk

    prep_kernel<<<12800, 256, 0, stream>>>(q, k, v, wq, wk, wv, wfc, Xq, Xk, Xv, Wcat);
    proj_kernel<<<1536, 256, 0, stream>>>(Xq, Xk, Xv, Wcat, Qb, Kb, Vt);
    attn_kernel<<<1024, 256, 0, stream>>>(Qb, Kb, Vt, Os);
    fc_kernel<<<512, 256, 0, stream>>>(Os, Wcat + 786432, Y);
    ln_kernel<<<4096, 256, 0, stream>>>(Y, Xq, gamma, beta, out);
}

// Round 18
// 120.229 us; speedup vs baseline: 1.2773x; 1.2773x over previous
//
#include <hip/hip_runtime.h>
#include <hip/hip_bf16.h>
#include <stdint.h>

// ---------- types & helpers ----------
typedef __attribute__((ext_vector_type(8))) short bf16x8;    // 8 bf16 (4 VGPRs)
typedef __attribute__((ext_vector_type(4))) float f32x4;     // 16x16 MFMA acc
typedef __attribute__((ext_vector_type(16))) float f32x16;   // 32x32 MFMA acc
typedef unsigned int u32;

#define MFMA16(a,b,c) __builtin_amdgcn_mfma_f32_16x16x32_bf16((a),(b),(c),0,0,0)
#define MFMA32(a,b,c) __builtin_amdgcn_mfma_f32_32x32x16_bf16((a),(b),(c),0,0,0)

__device__ __forceinline__ unsigned short f2bf(float f) {
    unsigned u = __float_as_uint(f);
    u = (u + 0x7FFFu + ((u >> 16) & 1u)) >> 16;   // RNE
    return (unsigned short)u;
}
__device__ __forceinline__ float bf2f(unsigned short h) {
    return __uint_as_float(((unsigned)h) << 16);
}
// 2x f32 -> packed bf16 pair (RNE), single VALU op
__device__ __forceinline__ u32 cvt_pk_bf16(float lo, float hi) {
    u32 r;
    asm("v_cvt_pk_bf16_f32 %0, %1, %2" : "=v"(r) : "v"(lo), "v"(hi));
    return r;
}
// async global->LDS, 16B per lane; lds base must be wave-uniform
__device__ __forceinline__ void gload16(const unsigned short* gp, unsigned short* lp) {
    __builtin_amdgcn_global_load_lds(
        (const __attribute__((address_space(1))) u32*)gp,
        (__attribute__((address_space(3))) u32*)lp, 16, 0, 0);
}
// bijective XCD chunking: nwg = q8*8
__device__ __forceinline__ int xcd_swz(int bid, int q8) {
    return (bid & 7) * q8 + (bid >> 3);
}

// Problem constants: 32 flattened batch, T=512, D=512, H=8, DK=DV=64

// ---------- kernel 0: fp32 -> bf16 prepass, one chunk per thread ----------
__global__ __launch_bounds__(256) void prep_kernel(
    const float* __restrict__ q, const float* __restrict__ k, const float* __restrict__ v,
    const float* __restrict__ wq, const float* __restrict__ wk, const float* __restrict__ wv,
    const float* __restrict__ wfc,
    unsigned short* __restrict__ Xq, unsigned short* __restrict__ Xk, unsigned short* __restrict__ Xv,
    unsigned short* __restrict__ Wcat)
{
    const long c = (long)blockIdx.x * 256 + threadIdx.x;
    const float* src;
    unsigned short* dst;
    long off;
    if (c < 3145728) {                 // X tensors: 1,048,576 chunks each
        const int t = (int)(c >> 20);
        off = (c & 1048575) * 8;
        src = (t == 0) ? q : (t == 1) ? k : v;
        dst = (t == 0) ? Xq : (t == 1) ? Xk : Xv;
    } else {                           // weights: 32768 chunks each
        const long c2 = c - 3145728;
        const int w = (int)(c2 >> 15);
        off = (c2 & 32767) * 8;
        src = (w == 0) ? wq : (w == 1) ? wk : (w == 2) ? wv : wfc;
        dst = Wcat + (long)w * 262144;
    }
    const float4 a = *(const float4*)(src + off);
    const float4 b = *(const float4*)(src + off + 4);
    uint4 pk;
    pk.x = (u32)f2bf(a.x) | ((u32)f2bf(a.y) << 16);
    pk.y = (u32)f2bf(a.z) | ((u32)f2bf(a.w) << 16);
    pk.z = (u32)f2bf(b.x) | ((u32)f2bf(b.y) << 16);
    pk.w = (u32)f2bf(b.z) | ((u32)f2bf(b.w) << 16);
    *(uint4*)(dst + off) = pk;
}

// ---------- GEMM body: 2-phase prefetch dbuf, BK=64 (proven best: r13/r16) ----------
// Five structural alternatives (fused-cvt r8, counted-vmcnt r9, fp32-LDS r10,
// BK=32 r14, A-direct-regs r17) all regressed; gload_lds both operands +
// one __syncthreads per K-step is the local optimum for this shape.
__device__ __forceinline__ void gemm_body(
    const unsigned short* __restrict__ A, const unsigned short* __restrict__ Bm,
    unsigned short* __restrict__ out, int mode, float scale,
    unsigned short* As0, unsigned short* Bs0,
    unsigned short* As1, unsigned short* Bs1,
    int m0, int n0)
{
    const int tid = threadIdx.x, wid = tid >> 6, lane = tid & 63;
    const int wm = wid >> 1, wn = wid & 1;          // 2x2 waves, 64x64 each
    const int g = lane >> 4, cc = lane & 15;

    f32x4 acc[4][4];
    #pragma unroll
    for (int a = 0; a < 4; a++)
        #pragma unroll
        for (int b = 0; b < 4; b++)
            acc[a][b] = (f32x4){0.f, 0.f, 0.f, 0.f};

    auto STAGE = [&](unsigned short* As, unsigned short* Bs, int k0) {
        #pragma unroll
        for (int j = 0; j < 4; j++) {
            const int sb = j * 256 + wid * 64;       // wave-uniform slot base
            const int s = sb + lane;
            const int r = s >> 3;
            const int cd = (s & 7) ^ (r & 7);        // pre-swizzled source block
            gload16(A  + (size_t)(m0 + r) * 512 + k0 + cd * 8, As + (size_t)sb * 8);
            gload16(Bm + (size_t)(n0 + r) * 512 + k0 + cd * 8, Bs + (size_t)sb * 8);
        }
    };

    STAGE(As0, Bs0, 0);
    __syncthreads();

    #pragma unroll
    for (int t = 0; t < 8; t++) {
        unsigned short* Ac = (t & 1) ? As1 : As0;
        unsigned short* Bc = (t & 1) ? Bs1 : Bs0;
        if (t < 7)
            STAGE((t & 1) ? As0 : As1, (t & 1) ? Bs0 : Bs1, (t + 1) * 64);

        #pragma unroll
        for (int kc = 0; kc < 2; kc++) {
            bf16x8 af[4], bfr[4];
            #pragma unroll
            for (int mf = 0; mf < 4; mf++) {
                const int r = wm * 64 + mf * 16 + cc;
                af[mf] = *(const bf16x8*)(Ac + r * 64 + (((kc * 4 + g) ^ (r & 7)) * 8));
            }
            #pragma unroll
            for (int nf = 0; nf < 4; nf++) {
                const int r = wn * 64 + nf * 16 + cc;
                bfr[nf] = *(const bf16x8*)(Bc + r * 64 + (((kc * 4 + g) ^ (r & 7)) * 8));
            }
            __builtin_amdgcn_s_setprio(1);
            #pragma unroll
            for (int mf = 0; mf < 4; mf++)
                #pragma unroll
                for (int nf = 0; nf < 4; nf++)
                    acc[mf][nf] = MFMA16(af[mf], bfr[nf], acc[mf][nf]);
            __builtin_amdgcn_s_setprio(0);
        }
        __syncthreads();
    }

    #pragma unroll
    for (int mf = 0; mf < 4; mf++) {
        const int rg = m0 + wm * 64 + mf * 16 + g * 4;
        const int t0 = rg & 511, bI = rg >> 9;
        #pragma unroll
        for (int nf = 0; nf < 4; nf++) {
            const int col = n0 + wn * 64 + nf * 16 + cc;
            if (mode == 0) {
                const int h = col >> 6, dd = col & 63;
                const size_t base = ((size_t)((bI * 8 + h) * 512 + t0)) * 64 + dd;
                #pragma unroll
                for (int i = 0; i < 4; i++)
                    out[base + (size_t)i * 64] = f2bf(acc[mf][nf][i] * scale);
            } else if (mode == 1) {
                const int h = col >> 6, dd = col & 63;
                const size_t base = ((size_t)((bI * 8 + h) * 64 + dd)) * 512 + t0;
                uint2 pk;
                pk.x = (u32)f2bf(acc[mf][nf][0]) | ((u32)f2bf(acc[mf][nf][1]) << 16);
                pk.y = (u32)f2bf(acc[mf][nf][2]) | ((u32)f2bf(acc[mf][nf][3]) << 16);
                *(uint2*)(out + base) = pk;
            } else {
                #pragma unroll
                for (int i = 0; i < 4; i++)
                    out[(size_t)(rg + i) * 512 + col] = f2bf(acc[mf][nf][i]);
            }
        }
    }
}

// ---------- kernel 1a: merged Q/K/V projection GEMMs ----------
__global__ __launch_bounds__(256) void proj_kernel(
    const unsigned short* __restrict__ Xq, const unsigned short* __restrict__ Xk,
    const unsigned short* __restrict__ Xv, const unsigned short* __restrict__ Wcat,
    unsigned short* __restrict__ Qb, unsigned short* __restrict__ Kb,
    unsigned short* __restrict__ Vt)
{
    __shared__ __align__(16) unsigned short As[2][128 * 64];
    __shared__ __align__(16) unsigned short Bs[2][128 * 64];
    const int work = xcd_swz(blockIdx.x, 192);       // nwg = 1536
    const int x = work & 3, y = (work >> 2) & 127, z = work >> 9;
    const unsigned short* A = (z == 0) ? Xq : (z == 1) ? Xk : Xv;
    const unsigned short* B = Wcat + (size_t)z * 262144;
    unsigned short* out = (z == 0) ? Qb : (z == 1) ? Kb : Vt;
    const int mode = (z == 2) ? 1 : 0;
    const float scale = (z == 0) ? 0.125f : 1.0f;
    gemm_body(A, B, out, mode, scale, As[0], Bs[0], As[1], Bs[1], y * 128, x * 128);
}

// ---------- kernel 1b: fc GEMM ----------
__global__ __launch_bounds__(256) void fc_kernel(
    const unsigned short* __restrict__ Os, const unsigned short* __restrict__ Wfc,
    unsigned short* __restrict__ Y)
{
    __shared__ __align__(16) unsigned short As[2][128 * 64];
    __shared__ __align__(16) unsigned short Bs[2][128 * 64];
    const int work = xcd_swz(blockIdx.x, 64);        // nwg = 512
    const int x = work & 3, y = work >> 2;
    gemm_body(Os, Wfc, Y, 2, 1.0f, As[0], Bs[0], As[1], Bs[1], y * 128, x * 128);
}

// ---------- kernel 2: flash attention, 32x32 swapped-QK^T, P-in-registers ----------
// (r16-verified: single-buffered staging, permlane32_swap half-exchange)
__global__ __launch_bounds__(256) void attn_kernel(
    const unsigned short* __restrict__ Qb, const unsigned short* __restrict__ Kb,
    const unsigned short* __restrict__ Vt, unsigned short* __restrict__ Os)
{
    __shared__ __align__(16) unsigned short Ks[64 * 64];   // 8 KB
    __shared__ __align__(16) unsigned short Vs[64 * 64];   // 8 KB

    const int work = xcd_swz(blockIdx.x, 128);       // nwg = 1024
    const int qt = work & 3, bh = work >> 2;
    const int tid = threadIdx.x;
    const int wid = tid >> 6, lane = tid & 63;
    const int l31 = lane & 31, hi = lane >> 5;

    const unsigned short* Qp = Qb + (size_t)bh * 512 * 64;
    const unsigned short* Kp = Kb + (size_t)bh * 512 * 64;
    const unsigned short* Vp = Vt + (size_t)bh * 64 * 512;

    const int q0 = qt * 128 + wid * 32;              // wave covers q0..q0+31

    bf16x8 qf[4];
    #pragma unroll
    for (int c = 0; c < 4; c++)
        qf[c] = *(const bf16x8*)(Qp + (size_t)(q0 + l31) * 64 + c * 16 + hi * 8);

    f32x16 o0, o1;                                   // O[q regs][dv=l31 / 32+l31]
    #pragma unroll
    for (int r = 0; r < 16; r++) { o0[r] = 0.f; o1[r] = 0.f; }
    float lrun = 0.f;

    const int sb = wid * 64;
    const int s1 = sb + lane, r1 = s1 >> 3, cd1 = (s1 & 7) ^ (r1 & 7);
    const int s2 = sb + 256 + lane, r2 = s2 >> 3, cd2 = (s2 & 7) ^ (r2 & 7);

    const int swz0 = l31 & 7;

    for (int kt = 0; kt < 8; kt++) {
        gload16(Kp + (size_t)(kt * 64 + r1) * 64 + cd1 * 8, Ks + (size_t)sb * 8);
        gload16(Kp + (size_t)(kt * 64 + r2) * 64 + cd2 * 8, Ks + (size_t)(sb + 256) * 8);
        gload16(Vp + (size_t)r1 * 512 + kt * 64 + cd1 * 8, Vs + (size_t)sb * 8);
        gload16(Vp + (size_t)r2 * 512 + kt * 64 + cd2 * 8, Vs + (size_t)(sb + 256) * 8);
        __syncthreads();

        f32x16 sT0, sT1;
        #pragma unroll
        for (int r = 0; r < 16; r++) { sT0[r] = 0.f; sT1[r] = 0.f; }
        __builtin_amdgcn_s_setprio(1);
        #pragma unroll
        for (int c = 0; c < 4; c++) {
            const int cs = c * 2 + hi;
            bf16x8 kf0 = *(const bf16x8*)(Ks + l31 * 64 + ((cs ^ swz0) * 8));
            bf16x8 kf1 = *(const bf16x8*)(Ks + (32 + l31) * 64 + ((cs ^ swz0) * 8));
            sT0 = MFMA32(kf0, qf[c], sT0);
            sT1 = MFMA32(kf1, qf[c], sT1);
        }
        __builtin_amdgcn_s_setprio(0);

        // shift-free softmax numerator; pack P to bf16 pairs (lane-local)
        u32 wA[8], wB[8];
        #pragma unroll
        for (int j = 0; j < 8; j++) {
            float a0 = __expf(sT0[2 * j]), a1 = __expf(sT0[2 * j + 1]);
            float b0 = __expf(sT1[2 * j]), b1 = __expf(sT1[2 * j + 1]);
            lrun += (a0 + a1) + (b0 + b1);
            wA[j] = cvt_pk_bf16(a0, a1);
            wB[j] = cvt_pk_bf16(b0, b1);
        }
        // half-exchange via permlane32_swap: after swap(w[jb+i], w[jb+i+2]),
        // w[jb+i] holds PV A-fragment word i for this lane.
        #pragma unroll
        for (int jb = 0; jb < 8; jb += 4) {
            asm("v_permlane32_swap_b32 %0, %1" : "+v"(wA[jb + 0]), "+v"(wA[jb + 2]));
            asm("v_permlane32_swap_b32 %0, %1" : "+v"(wA[jb + 1]), "+v"(wA[jb + 3]));
            asm("v_permlane32_swap_b32 %0, %1" : "+v"(wB[jb + 0]), "+v"(wB[jb + 2]));
            asm("v_permlane32_swap_b32 %0, %1" : "+v"(wB[jb + 1]), "+v"(wB[jb + 3]));
        }

        __builtin_amdgcn_s_setprio(1);
        #pragma unroll
        for (int ck = 0; ck < 4; ck++) {
            const u32* w = (ck < 2) ? wA : wB;
            const int jb = (ck & 1) * 4;
            union { u32 u[4]; bf16x8 v; } pa;
            pa.u[0] = w[jb + 0];
            pa.u[1] = w[jb + 1];
            pa.u[2] = w[jb + 2];
            pa.u[3] = w[jb + 3];
            const int cs = ck * 2 + hi;
            bf16x8 vb0 = *(const bf16x8*)(Vs + l31 * 64 + ((cs ^ swz0) * 8));
            bf16x8 vb1 = *(const bf16x8*)(Vs + (32 + l31) * 64 + ((cs ^ swz0) * 8));
            o0 = MFMA32(pa.v, vb0, o0);
            o1 = MFMA32(pa.v, vb1, o1);
        }
        __builtin_amdgcn_s_setprio(0);
        __syncthreads();
    }

    const float lsum = lrun + __shfl_xor(lrun, 32);
    const float inv = 1.0f / lsum;
    float iv[16];
    #pragma unroll
    for (int qd = 0; qd < 4; qd++)
        #pragma unroll
        for (int i = 0; i < 4; i++)
            iv[qd * 4 + i] = __shfl(inv, qd * 8 + 4 * hi + i);

    const int b = bh >> 3, h = bh & 7;
    #pragma unroll
    for (int dvt = 0; dvt < 2; dvt++) {
        const f32x16& o = dvt ? o1 : o0;
        const int dv = dvt * 32 + l31;
        const size_t rowbase = ((size_t)b * 512 + h * 64 + dv) * 512;
        #pragma unroll
        for (int qd = 0; qd < 4; qd++) {
            uint2 pk;
            pk.x = cvt_pk_bf16(o[qd * 4 + 0] * iv[qd * 4 + 0], o[qd * 4 + 1] * iv[qd * 4 + 1]);
            pk.y = cvt_pk_bf16(o[qd * 4 + 2] * iv[qd * 4 + 2], o[qd * 4 + 3] * iv[qd * 4 + 3]);
            *(uint2*)(Os + rowbase + q0 + qd * 8 + 4 * hi) = pk;
        }
    }
}

// ---------- kernel 3: residual + LayerNorm (bf16 residual from Xq) ----------
__global__ __launch_bounds__(256) void ln_kernel(
    const unsigned short* __restrict__ y, const unsigned short* __restrict__ residb,
    const float* __restrict__ gamma, const float* __restrict__ beta,
    float* __restrict__ out)
{
    const int wid = threadIdx.x >> 6, lane = threadIdx.x & 63;
    const int row = blockIdx.x * 4 + wid;

    const bf16x8 yv = *(const bf16x8*)(y + (size_t)row * 512 + lane * 8);
    const bf16x8 rv = *(const bf16x8*)(residb + (size_t)row * 512 + lane * 8);
    float x[8];
    #pragma unroll
    for (int j = 0; j < 8; j++)
        x[j] = bf2f((unsigned short)yv[j]) + bf2f((unsigned short)rv[j]);

    float s = 0.f, sq = 0.f;
    #pragma unroll
    for (int j = 0; j < 8; j++) { s += x[j]; sq += x[j] * x[j]; }
    #pragma unroll
    for (int d = 1; d < 64; d <<= 1) {
        s += __shfl_xor(s, d);
        sq += __shfl_xor(sq, d);
    }
    const float mu = s * (1.0f / 512.0f);
    const float var = sq * (1.0f / 512.0f) - mu * mu;
    const float rs = rsqrtf(var + 1e-6f);

    #pragma unroll
    for (int j = 0; j < 2; j++) {
        const int colb = lane * 8 + j * 4;
        const float4 gg = *(const float4*)(gamma + colb);
        const float4 bb = *(const float4*)(beta + colb);
        float4 ov;
        ov.x = (x[j * 4 + 0] - mu) * rs * gg.x + bb.x;
        ov.y = (x[j * 4 + 1] - mu) * rs * gg.y + bb.y;
        ov.z = (x[j * 4 + 2] - mu) * rs * gg.z + bb.z;
        ov.w = (x[j * 4 + 3] - mu) * rs * gg.w + bb.w;
        *(float4*)(out + (size_t)row * 512 + colb) = ov;
    }
}

// ---------- launch ----------
// ws (98 MB): Xq | Xk | Xv | Qb | Kb | Vt (16 MB each) | Wcat (2 MB)
// aliases: Os = Xv (dead after proj), Y = Xk (dead after proj); Xq stays
// alive as the bf16 residual for ln.
extern "C" void kernel_launch(void* const* d_in, const int* in_sizes, int n_in,
                              void* d_out, int out_size, void* d_ws, size_t ws_size,
                              hipStream_t stream) {
    const float* q     = (const float*)d_in[0];
    const float* k     = (const float*)d_in[1];
    const float* v     = (const float*)d_in[2];
    const float* wq    = (const float*)d_in[3];
    const float* wk    = (const float*)d_in[4];
    const float* wv    = (const float*)d_in[5];
    const float* wfc   = (const float*)d_in[6];
    const float* gamma = (const float*)d_in[7];
    const float* beta  = (const float*)d_in[8];
    float* out = (float*)d_out;

    char* ws = (char*)d_ws;
    const size_t SEG = 16777216;
    unsigned short* Xq   = (unsigned short*)(ws);
    unsigned short* Xk   = (unsigned short*)(ws + SEG);
    unsigned short* Xv   = (unsigned short*)(ws + 2 * SEG);
    unsigned short* Qb   = (unsigned short*)(ws + 3 * SEG);
    unsigned short* Kb   = (unsigned short*)(ws + 4 * SEG);
    unsigned short* Vt   = (unsigned short*)(ws + 5 * SEG);
    unsigned short* Wcat = (unsigned short*)(ws + 6 * SEG);
    unsigned short* Os = Xv;   // attn output reuses Xv
    unsigned short* Y  = Xk;   // fc output reuses Xk

    prep_kernel<<<12800, 256, 0, stream>>>(q, k, v, wq, wk, wv, wfc, Xq, Xk, Xv, Wcat);
    proj_kernel<<<1536, 256, 0, stream>>>(Xq, Xk, Xv, Wcat, Qb, Kb, Vt);
    attn_kernel<<<1024, 256, 0, stream>>>(Qb, Kb, Vt, Os);
    fc_kernel<<<512, 256, 0, stream>>>(Os, Wcat + 786432, Y);
    ln_kernel<<<4096, 256, 0, stream>>>(Y, Xq, gamma, beta, out);
}